// Round 6
// baseline (686.714 us; speedup 1.0000x reference)
//
#include <hip/hip_runtime.h>

// Problem constants
#define BATCH 4
#define NNODE 50000
#define NEDGE 1600000
#define F_IN 12
#define F_OUT 48
#define SEQ 12

#define BNODE 128                               // dst-nodes per bucket (pow2)
#define NBUCK ((NNODE + BNODE - 1) / BNODE)     // 391 buckets per batch
#define NBINS (BATCH * NBUCK)                   // 1564
#define SCAN_N 2048                             // padded single-block scan
#define EBLK 4096                               // edges per count/fill block
#define EPB (EBLK / 256)
#define NFB ((NEDGE + EBLK - 1) / EBLK)         // 391

typedef float f4v __attribute__((ext_vector_type(4)));

// ---------- CSR build: two-level bucketing ----------

__global__ void __launch_bounds__(256) k_zero(int* __restrict__ cnt) {
    int i = blockIdx.x * 256 + threadIdx.x;
    if (i < SCAN_N) cnt[i] = 0;
}

__global__ void __launch_bounds__(256) k_count(const int* __restrict__ ei,
                                               int* __restrict__ cnt) {
    __shared__ int h[NBUCK];
    int t = threadIdx.x;
    for (int i = t; i < NBUCK; i += 256) h[i] = 0;
    __syncthreads();
    int b = blockIdx.y;
    int e0 = blockIdx.x * EBLK;
    const int* dsts = ei + ((size_t)b * 2 + 1) * NEDGE;
    for (int it = 0; it < EPB; ++it) {
        int e = e0 + it * 256 + t;
        if (e < NEDGE) atomicAdd(&h[dsts[e] >> 7], 1);
    }
    __syncthreads();
    for (int i = t; i < NBUCK; i += 256) {
        int c = h[i];
        if (c) atomicAdd(&cnt[b * NBUCK + i], c);
    }
}

__global__ void __launch_bounds__(256) k_scan(const int* __restrict__ cnt,
                                              int* __restrict__ off,
                                              int* __restrict__ cur) {
    __shared__ int w[256];
    int t = threadIdx.x;
    int base = t * 8;
    int loc[8];
    int s = 0;
#pragma unroll
    for (int j = 0; j < 8; j++) { loc[j] = cnt[base + j]; s += loc[j]; }
    w[t] = s;
    __syncthreads();
    for (int d = 1; d < 256; d <<= 1) {
        int v = (t >= d) ? w[t - d] : 0;
        __syncthreads();
        w[t] += v;
        __syncthreads();
    }
    int run = w[t] - s;
#pragma unroll
    for (int j = 0; j < 8; j++) {
        int i = base + j;
        off[i] = run;
        if (i < NBINS) cur[i] = run;
        run += loc[j];
    }
}

__global__ void __launch_bounds__(256) k_fill(const int* __restrict__ ei,
                                              const float* __restrict__ ew,
                                              int* __restrict__ cur,
                                              int2* __restrict__ rec) {
    __shared__ int h[512];
    __shared__ int loff[512];
    __shared__ int gbase[NBUCK];
    __shared__ int2 srec[EBLK];
    __shared__ short sbuck[EBLK];
    __shared__ int w[256];

    int t = threadIdx.x;
    int b = blockIdx.y;
    int e0 = blockIdx.x * EBLK;
    for (int i = t; i < 512; i += 256) h[i] = 0;
    __syncthreads();

    const size_t ebase = (size_t)b * 2 * NEDGE;
    const int* srcs = ei + ebase;
    const int* dsts = ei + ebase + NEDGE;
    const float* ws = ew + (size_t)b * NEDGE;

    int2 myrec[EPB];
    int mypk[EPB];
#pragma unroll
    for (int it = 0; it < EPB; ++it) {
        int e = e0 + it * 256 + t;
        int valid = e < NEDGE;
        int src = 0, dst = 0;
        float wv = 0.0f;
        if (valid) { src = srcs[e]; dst = dsts[e]; wv = ws[e]; }
        int g = dst >> 7;
        int r = 0;
        if (valid) r = atomicAdd(&h[g], 1);
        myrec[it] = make_int2(((dst & (BNODE - 1)) << 16) | src, __float_as_int(wv));
        mypk[it] = valid ? ((g << 16) | r) : -1;
    }
    __syncthreads();

    int c0 = h[2 * t], c1 = h[2 * t + 1];
    int ls = c0 + c1;
    w[t] = ls;
    __syncthreads();
    for (int d = 1; d < 256; d <<= 1) {
        int v = (t >= d) ? w[t - d] : 0;
        __syncthreads();
        w[t] += v;
        __syncthreads();
    }
    int excl = w[t] - ls;
    loff[2 * t] = excl;
    loff[2 * t + 1] = excl + c0;
    __syncthreads();

    for (int i = t; i < NBUCK; i += 256) {
        int c = h[i];
        if (c) gbase[i] = atomicAdd(&cur[b * NBUCK + i], c);
    }
#pragma unroll
    for (int it = 0; it < EPB; ++it) {
        int pk = mypk[it];
        if (pk >= 0) {
            int g = pk >> 16, r = pk & 0xFFFF;
            int p = loff[g] + r;
            srec[p] = myrec[it];
            sbuck[p] = (short)g;
        }
    }
    __syncthreads();

    int nvalid = min(EBLK, NEDGE - e0);
    for (int j = t; j < nvalid; j += 256) {
        int g = sbuck[j];
        rec[gbase[g] + (j - loff[g])] = srec[j];
    }
}

// ---------- numeric phase ----------

__global__ void __launch_bounds__(256) k_deg(const int* __restrict__ off,
                                             const int2* __restrict__ rec,
                                             float* __restrict__ dinv) {
    __shared__ float sdeg[BNODE];
    int t = threadIdx.x;
    int bin = blockIdx.x;
    int b = bin / NBUCK, g = bin - b * NBUCK;
    if (t < BNODE) sdeg[t] = 1.0f;
    __syncthreads();
    const unsigned long long* rp = (const unsigned long long*)rec;
    int s = off[bin], e = off[bin + 1];
    for (int j = s + t; j < e; j += 256) {
        unsigned long long rv = __builtin_nontemporal_load(rp + j);
        int key = (int)(rv & 0xFFFFFFFFull);
        int wbits = (int)(rv >> 32);
        atomicAdd(&sdeg[key >> 16], __int_as_float(wbits));
    }
    __syncthreads();
    if (t < BNODE) {
        int n = g * BNODE + t;
        if (n < NNODE) dinv[b * NNODE + n] = rsqrtf(sdeg[t]);
    }
}

// xs[n] = dinv[n] * x[n], padded to 16 floats (one 64B line per row)
__global__ void __launch_bounds__(256) k_stage(const float* __restrict__ x,
                                               const float* __restrict__ dinv,
                                               float* __restrict__ xs) {
    int i = blockIdx.x * 256 + threadIdx.x;
    if (i >= BATCH * NNODE) return;
    float di = dinv[i];
    const float4* x4 = (const float4*)(x + (size_t)i * F_IN);
    float4 a = x4[0], b = x4[1], c = x4[2];
    float4* o = (float4*)(xs + (size_t)i * 16);
    o[0] = make_float4(a.x * di, a.y * di, a.z * di, a.w * di);
    o[1] = make_float4(b.x * di, b.y * di, b.z * di, b.w * di);
    o[2] = make_float4(c.x * di, c.y * di, c.z * di, c.w * di);
    o[3] = make_float4(0.f, 0.f, 0.f, 0.f);
}

// 4 lanes per record: one 64B-line gather per record; acc rows padded to 17.
__global__ void __launch_bounds__(256) k_gather(const int* __restrict__ off,
                                                const int2* __restrict__ rec,
                                                const float* __restrict__ xs,
                                                const float* __restrict__ dinv,
                                                const float* __restrict__ Wm,
                                                const float* __restrict__ bias,
                                                float* __restrict__ out) {
    __shared__ float acc[BNODE * 17];
    __shared__ float sW[F_IN * F_OUT];
    __shared__ float sb[F_OUT];
    int t = threadIdx.x;

    // XCD-batch affinity: blockIdx&7 = XCD (round-robin), batch = xcd>>1
    int bid = blockIdx.x;
    int xcd = bid & 7;
    int b = xcd >> 1;
    int gl = ((bid >> 3) << 1) + (xcd & 1);
    if (gl >= NBUCK) return;
    int bin = b * NBUCK + gl;

    for (int i = t; i < BNODE * 17; i += 256) acc[i] = 0.0f;
    for (int i = t; i < F_IN * F_OUT; i += 256) sW[i] = Wm[i];
    if (t < F_OUT) sb[t] = bias[t];
    __syncthreads();

    const f4v* xs4 = (const f4v*)xs + (size_t)b * NNODE * 4;
    const unsigned long long* rp = (const unsigned long long*)rec;
    int gid = t >> 2, l = t & 3;
    int s = off[bin], e = off[bin + 1];

    for (int j0 = s; j0 < e; j0 += 128) {
        int j1 = j0 + gid, j2 = j0 + 64 + gid;
        unsigned long long rv1 = 0, rv2 = 0;
        if (j1 < e) rv1 = __builtin_nontemporal_load(rp + j1);
        if (j2 < e) rv2 = __builtin_nontemporal_load(rp + j2);
        int k1 = (int)(rv1 & 0xFFFFFFFFull), k2 = (int)(rv2 & 0xFFFFFFFFull);
        float c1 = __int_as_float((int)(rv1 >> 32));
        float c2 = __int_as_float((int)(rv2 >> 32));
        f4v v1 = xs4[(size_t)(k1 & 0xFFFF) * 4 + l];
        f4v v2 = xs4[(size_t)(k2 & 0xFFFF) * 4 + l];
        if (l < 3) {
            if (j1 < e) {
                float* a = acc + (k1 >> 16) * 17 + l * 4;
                atomicAdd(a + 0, c1 * v1.x);
                atomicAdd(a + 1, c1 * v1.y);
                atomicAdd(a + 2, c1 * v1.z);
                atomicAdd(a + 3, c1 * v1.w);
            }
            if (j2 < e) {
                float* a = acc + (k2 >> 16) * 17 + l * 4;
                atomicAdd(a + 0, c2 * v2.x);
                atomicAdd(a + 1, c2 * v2.y);
                atomicAdd(a + 2, c2 * v2.z);
                atomicAdd(a + 3, c2 * v2.w);
            }
        }
    }
    __syncthreads();

    // finalize: 2 threads/node; out_feat = di*(acc + xs_self) (xs=dinv*x folds self-loop)
    int node = t >> 1, half = t & 1;
    int n = gl * BNODE + node;
    if (n >= NNODE) return;
    float di = dinv[b * NNODE + n];
    const f4v* xn4 = xs4 + (size_t)n * 4;
    f4v s0 = xn4[0], s1 = xn4[1], s2 = xn4[2];
    float xsn[F_IN] = {s0.x, s0.y, s0.z, s0.w, s1.x, s1.y, s1.z, s1.w,
                       s2.x, s2.y, s2.z, s2.w};
    float a[F_IN];
#pragma unroll
    for (int k = 0; k < F_IN; k++)
        a[k] = di * (acc[node * 17 + k] + xsn[k]);

    float h[24];
#pragma unroll
    for (int j = 0; j < 24; j++) {
        int jj = half * 24 + j;
        float v = sb[jj];
#pragma unroll
        for (int k = 0; k < F_IN; k++) v = fmaf(a[k], sW[k * F_OUT + jj], v);
        h[j] = v;
    }
    f4v* out4 = (f4v*)out;
#pragma unroll
    for (int q = 0; q < 6; q++) {
        int s_idx = half * 6 + q;
        f4v v = {h[q * 4 + 0], h[q * 4 + 1], h[q * 4 + 2], h[q * 4 + 3]};
        __builtin_nontemporal_store(v, out4 + (size_t)(b * SEQ + s_idx) * NNODE + n);
    }
}

extern "C" void kernel_launch(void* const* d_in, const int* in_sizes, int n_in,
                              void* d_out, int out_size, void* d_ws, size_t ws_size,
                              hipStream_t stream) {
    const float* x  = (const float*)d_in[0];
    const int*   ei = (const int*)d_in[1];
    const float* ew = (const float*)d_in[2];
    const float* Wm = (const float*)d_in[3];
    const float* bv = (const float*)d_in[4];
    float* out = (float*)d_out;

    // Workspace: rec 51.2MB | xs 12.8MB | cnt | off | cur | dinv  (~64.9MB)
    int2*  rec = (int2*)d_ws;
    float* xs  = (float*)(rec + (size_t)BATCH * NEDGE);
    int*   cnt = (int*)(xs + (size_t)BATCH * NNODE * 16);
    int*   off = cnt + SCAN_N;
    int*   cur = off + SCAN_N;
    float* dinv = (float*)(cur + NBINS);

    k_zero<<<SCAN_N / 256, 256, 0, stream>>>(cnt);
    {
        dim3 grid(NFB, BATCH);
        k_count<<<grid, 256, 0, stream>>>(ei, cnt);
    }
    k_scan<<<1, 256, 0, stream>>>(cnt, off, cur);
    {
        dim3 grid(NFB, BATCH);
        k_fill<<<grid, 256, 0, stream>>>(ei, ew, cur, rec);
    }
    k_deg<<<NBINS, 256, 0, stream>>>(off, rec, dinv);
    k_stage<<<(BATCH * NNODE + 255) / 256, 256, 0, stream>>>(x, dinv, xs);
    k_gather<<<8 * 196, 256, 0, stream>>>(off, rec, xs, dinv, Wm, bv, out);
}

// Round 10
// 312.601 us; speedup vs baseline: 2.1968x; 2.1968x over previous
//
#include <hip/hip_runtime.h>

// Problem constants
#define BATCH 4
#define NNODE 50000
#define NEDGE 1600000
#define F_IN 12
#define F_OUT 48
#define SEQ 12

#define BNODE 64                                // dst-nodes per bucket (pow2)
#define NBUCK ((NNODE + BNODE - 1) / BNODE)     // 782 buckets per batch
#define NBINS (BATCH * NBUCK)                   // 3128
#define SCAN_N 4096                             // padded single-block scan
#define EBLK 4096                               // edges per count/fill block
#define EPB (EBLK / 256)
#define NFB ((NEDGE + EBLK - 1) / EBLK)         // 391
#define CAPB 2560                               // LDS record capacity (~mean+11sigma)
#define MAXR (CAPB / 256)                       // 10 records max per thread

typedef float f4v __attribute__((ext_vector_type(4)));

// ---------- CSR build: two-level bucketing ----------

__global__ void __launch_bounds__(256) k_zero(int* __restrict__ cnt) {
    int i = blockIdx.x * 256 + threadIdx.x;
    if (i < SCAN_N) cnt[i] = 0;
}

__global__ void __launch_bounds__(256) k_count(const int* __restrict__ ei,
                                               int* __restrict__ cnt) {
    __shared__ int h[NBUCK];
    int t = threadIdx.x;
    for (int i = t; i < NBUCK; i += 256) h[i] = 0;
    __syncthreads();
    int b = blockIdx.y;
    int e0 = blockIdx.x * EBLK;
    const int* dsts = ei + ((size_t)b * 2 + 1) * NEDGE;
    for (int it = 0; it < EPB; ++it) {
        int e = e0 + it * 256 + t;
        if (e < NEDGE) atomicAdd(&h[dsts[e] >> 6], 1);
    }
    __syncthreads();
    for (int i = t; i < NBUCK; i += 256) {
        int c = h[i];
        if (c) atomicAdd(&cnt[b * NBUCK + i], c);
    }
}

__global__ void __launch_bounds__(256) k_scan(const int* __restrict__ cnt,
                                              int* __restrict__ off,
                                              int* __restrict__ cur) {
    __shared__ int w[256];
    int t = threadIdx.x;
    int base = t * 16;
    int loc[16];
    int s = 0;
#pragma unroll
    for (int j = 0; j < 16; j++) { loc[j] = cnt[base + j]; s += loc[j]; }
    w[t] = s;
    __syncthreads();
    for (int d = 1; d < 256; d <<= 1) {
        int v = (t >= d) ? w[t - d] : 0;
        __syncthreads();
        w[t] += v;
        __syncthreads();
    }
    int run = w[t] - s;
#pragma unroll
    for (int j = 0; j < 16; j++) {
        int i = base + j;
        off[i] = run;
        if (i < NBINS) cur[i] = run;
        run += loc[j];
    }
}

__global__ void __launch_bounds__(256) k_fill(const int* __restrict__ ei,
                                              const float* __restrict__ ew,
                                              int* __restrict__ cur,
                                              int2* __restrict__ rec) {
    __shared__ int h[1024];
    __shared__ int loff[1024];
    __shared__ int gbase[NBUCK];
    __shared__ int2 srec[EBLK];
    __shared__ short sbuck[EBLK];
    __shared__ int w[256];

    int t = threadIdx.x;
    int b = blockIdx.y;
    int e0 = blockIdx.x * EBLK;
    for (int i = t; i < 1024; i += 256) h[i] = 0;
    __syncthreads();

    const size_t ebase = (size_t)b * 2 * NEDGE;
    const int* srcs = ei + ebase;
    const int* dsts = ei + ebase + NEDGE;
    const float* ws = ew + (size_t)b * NEDGE;

    int2 myrec[EPB];
    int mypk[EPB];
#pragma unroll
    for (int it = 0; it < EPB; ++it) {
        int e = e0 + it * 256 + t;
        int valid = e < NEDGE;
        int src = 0, dst = 0;
        float wv = 0.0f;
        if (valid) { src = srcs[e]; dst = dsts[e]; wv = ws[e]; }
        int g = dst >> 6;
        int r = 0;
        if (valid) r = atomicAdd(&h[g], 1);
        myrec[it] = make_int2(((dst & (BNODE - 1)) << 16) | src, __float_as_int(wv));
        mypk[it] = valid ? ((g << 16) | r) : -1;
    }
    __syncthreads();

    // scan 1024 bucket counts (4 per thread)
    int c0 = h[4 * t], c1 = h[4 * t + 1], c2 = h[4 * t + 2], c3 = h[4 * t + 3];
    int ls = c0 + c1 + c2 + c3;
    w[t] = ls;
    __syncthreads();
    for (int d = 1; d < 256; d <<= 1) {
        int v = (t >= d) ? w[t - d] : 0;
        __syncthreads();
        w[t] += v;
        __syncthreads();
    }
    int excl = w[t] - ls;
    loff[4 * t] = excl;
    loff[4 * t + 1] = excl + c0;
    loff[4 * t + 2] = excl + c0 + c1;
    loff[4 * t + 3] = excl + c0 + c1 + c2;
    __syncthreads();

    for (int i = t; i < NBUCK; i += 256) {
        int c = h[i];
        if (c) gbase[i] = atomicAdd(&cur[b * NBUCK + i], c);
    }
#pragma unroll
    for (int it = 0; it < EPB; ++it) {
        int pk = mypk[it];
        if (pk >= 0) {
            int g = pk >> 16, r = pk & 0xFFFF;
            int p = loff[g] + r;
            srec[p] = myrec[it];
            sbuck[p] = (short)g;
        }
    }
    __syncthreads();

    int nvalid = min(EBLK, NEDGE - e0);
    for (int j = t; j < nvalid; j += 256) {
        int g = sbuck[j];
        rec[gbase[g] + (j - loff[g])] = srec[j];
    }
}

// ---------- numeric phase ----------

__global__ void __launch_bounds__(256) k_deg(const int* __restrict__ off,
                                             const int2* __restrict__ rec,
                                             float* __restrict__ dinv) {
    __shared__ float sdeg[BNODE];
    int t = threadIdx.x;
    int bin = blockIdx.x;
    int b = bin / NBUCK, g = bin - b * NBUCK;
    if (t < BNODE) sdeg[t] = 1.0f;
    __syncthreads();
    const unsigned long long* rp = (const unsigned long long*)rec;
    int s = off[bin], e = off[bin + 1];
    for (int j = s + t; j < e; j += 256) {
        unsigned long long rv = __builtin_nontemporal_load(rp + j);
        int key = (int)(rv & 0xFFFFFFFFull);
        atomicAdd(&sdeg[key >> 16], __int_as_float((int)(rv >> 32)));
    }
    __syncthreads();
    if (t < BNODE) {
        int n = g * BNODE + t;
        if (n < NNODE) dinv[b * NNODE + n] = rsqrtf(sdeg[t]);
    }
}

// xs[n] = dinv[n] * x[n], padded to 16 floats (one 64B line per row)
__global__ void __launch_bounds__(256) k_stage(const float* __restrict__ x,
                                               const float* __restrict__ dinv,
                                               float* __restrict__ xs) {
    int i = blockIdx.x * 256 + threadIdx.x;
    if (i >= BATCH * NNODE) return;
    float di = dinv[i];
    const float4* x4 = (const float4*)(x + (size_t)i * F_IN);
    float4 a = x4[0], b = x4[1], c = x4[2];
    float4* o = (float4*)(xs + (size_t)i * 16);
    o[0] = make_float4(a.x * di, a.y * di, a.z * di, a.w * di);
    o[1] = make_float4(b.x * di, b.y * di, b.z * di, b.w * di);
    o[2] = make_float4(c.x * di, c.y * di, c.z * di, c.w * di);
    o[3] = make_float4(0.f, 0.f, 0.f, 0.f);
}

// Per-bucket counting sort (int LDS atomics only) -> register accumulation
// (zero f32 LDS atomics) -> shfl combine -> W+b -> transposed store.
__global__ void __launch_bounds__(256) k_gather(const int* __restrict__ off,
                                                const int2* __restrict__ rec,
                                                const float* __restrict__ xs,
                                                const float* __restrict__ dinv,
                                                const float* __restrict__ Wm,
                                                const float* __restrict__ bias,
                                                float* __restrict__ out) {
    __shared__ int2 srec[CAPB];      // 20.5 KB node-sorted records
    __shared__ int hh[BNODE];
    __shared__ int basev[BNODE];
    __shared__ int wscan[BNODE];
    __shared__ float sW[F_IN * F_OUT];
    __shared__ float sb[F_OUT];

    int t = threadIdx.x;
    // XCD-batch affinity: blockIdx&7 = XCD, batch = xcd>>1
    int bid = blockIdx.x;
    int xcd = bid & 7;
    int b = xcd >> 1;
    int gl = ((bid >> 3) << 1) + (xcd & 1);   // 0..781, bijective over grid
    int bin = b * NBUCK + gl;

    for (int i = t; i < BNODE; i += 256) hh[i] = 0;
    for (int i = t; i < F_IN * F_OUT; i += 256) sW[i] = Wm[i];
    if (t < F_OUT) sb[t] = bias[t];
    __syncthreads();

    int s = off[bin], e = off[bin + 1];
    const unsigned long long* rp = (const unsigned long long*)rec;

    // phase 1: load records, rank by node via int atomic-return
    int2 myrec[MAXR];
    int mypk[MAXR];
#pragma unroll
    for (int i = 0; i < MAXR; i++) {
        mypk[i] = -1;
        int j = s + i * 256 + t;
        if (j < e) {
            unsigned long long rv = __builtin_nontemporal_load(rp + j);
            int key = (int)(rv & 0xFFFFFFFFull);
            myrec[i] = make_int2(key, (int)(rv >> 32));
            int node = key >> 16;
            int r = atomicAdd(&hh[node], 1);
            mypk[i] = (r << 8) | node;
        }
    }
    __syncthreads();

    // phase 2: exclusive scan of 64 node counts
    if (t < BNODE) wscan[t] = hh[t];
    __syncthreads();
    for (int d = 1; d < BNODE; d <<= 1) {
        int v = 0;
        if (t < BNODE && t >= d) v = wscan[t - d];
        __syncthreads();
        if (t < BNODE) wscan[t] += v;
        __syncthreads();
    }
    if (t < BNODE) basev[t] = wscan[t] - hh[t];
    __syncthreads();

    // phase 3: scatter node-sorted into LDS (no atomics)
#pragma unroll
    for (int i = 0; i < MAXR; i++) {
        int pk = mypk[i];
        if (pk >= 0) {
            int node = pk & 63;
            srec[basev[node] + (pk >> 8)] = myrec[i];
        }
    }
    __syncthreads();

    // phase 4: 4 threads per node, register accumulation over record subsets
    int node = t >> 2, par = t & 3;
    const f4v* xs4 = (const f4v*)xs + (size_t)b * NNODE * 4;
    float a[F_IN];
#pragma unroll
    for (int k = 0; k < F_IN; k++) a[k] = 0.0f;
    int rs = basev[node], re = rs + hh[node];
    for (int j = rs + par; j < re; j += 4) {
        int2 r = srec[j];
        int src = r.x & 0xFFFF;
        float wv = __int_as_float(r.y);
        const f4v* xp = xs4 + (size_t)src * 4;
        f4v v0 = xp[0], v1 = xp[1], v2 = xp[2];
        a[0] += wv * v0.x;  a[1] += wv * v0.y;  a[2]  += wv * v0.z;  a[3]  += wv * v0.w;
        a[4] += wv * v1.x;  a[5] += wv * v1.y;  a[6]  += wv * v1.z;  a[7]  += wv * v1.w;
        a[8] += wv * v2.x;  a[9] += wv * v2.y;  a[10] += wv * v2.z;  a[11] += wv * v2.w;
    }
    // butterfly combine across the 4 lanes of this node's group
#pragma unroll
    for (int k = 0; k < F_IN; k++) {
        a[k] += __shfl_xor(a[k], 1);
        a[k] += __shfl_xor(a[k], 2);
    }

    // phase 5: finalize (self-loop folded via xs = dinv*x), 12 outputs per lane
    int n = gl * BNODE + node;
    if (n >= NNODE) return;
    float di = dinv[b * NNODE + n];
    const f4v* xn = xs4 + (size_t)n * 4;
    f4v s0 = xn[0], s1 = xn[1], s2 = xn[2];
    float xsn[F_IN] = {s0.x, s0.y, s0.z, s0.w, s1.x, s1.y, s1.z, s1.w,
                       s2.x, s2.y, s2.z, s2.w};
#pragma unroll
    for (int k = 0; k < F_IN; k++) a[k] = di * (a[k] + xsn[k]);

    float hv[12];
#pragma unroll
    for (int j = 0; j < 12; j++) {
        int jj = par * 12 + j;
        float v = sb[jj];
#pragma unroll
        for (int k = 0; k < F_IN; k++) v = fmaf(a[k], sW[k * F_OUT + jj], v);
        hv[j] = v;
    }
    f4v* out4 = (f4v*)out;
#pragma unroll
    for (int q = 0; q < 3; q++) {
        int sq = par * 3 + q;
        f4v v = {hv[q * 4 + 0], hv[q * 4 + 1], hv[q * 4 + 2], hv[q * 4 + 3]};
        __builtin_nontemporal_store(v, out4 + (size_t)(b * SEQ + sq) * NNODE + n);
    }
}

extern "C" void kernel_launch(void* const* d_in, const int* in_sizes, int n_in,
                              void* d_out, int out_size, void* d_ws, size_t ws_size,
                              hipStream_t stream) {
    const float* x  = (const float*)d_in[0];
    const int*   ei = (const int*)d_in[1];
    const float* ew = (const float*)d_in[2];
    const float* Wm = (const float*)d_in[3];
    const float* bv = (const float*)d_in[4];
    float* out = (float*)d_out;

    // Workspace: rec 51.2MB | xs 12.8MB | cnt | off | cur | dinv  (~65MB)
    int2*  rec = (int2*)d_ws;
    float* xs  = (float*)(rec + (size_t)BATCH * NEDGE);
    int*   cnt = (int*)(xs + (size_t)BATCH * NNODE * 16);
    int*   off = cnt + SCAN_N;
    int*   cur = off + SCAN_N;
    float* dinv = (float*)(cur + NBINS);

    k_zero<<<SCAN_N / 256, 256, 0, stream>>>(cnt);
    {
        dim3 grid(NFB, BATCH);
        k_count<<<grid, 256, 0, stream>>>(ei, cnt);
    }
    k_scan<<<1, 256, 0, stream>>>(cnt, off, cur);
    {
        dim3 grid(NFB, BATCH);
        k_fill<<<grid, 256, 0, stream>>>(ei, ew, cur, rec);
    }
    k_deg<<<NBINS, 256, 0, stream>>>(off, rec, dinv);
    k_stage<<<(BATCH * NNODE + 255) / 256, 256, 0, stream>>>(x, dinv, xs);
    k_gather<<<8 * (NBUCK / 2), 256, 0, stream>>>(off, rec, xs, dinv, Wm, bv, out);
}

// Round 13
// 291.398 us; speedup vs baseline: 2.3566x; 1.0728x over previous
//
#include <hip/hip_runtime.h>

// Problem constants
#define BATCH 4
#define NNODE 50000
#define NEDGE 1600000
#define F_IN 12
#define F_OUT 48
#define SEQ 12

#define BNODE 64                                // dst-nodes per bucket (pow2)
#define NBUCK ((NNODE + BNODE - 1) / BNODE)     // 782 buckets per batch
#define NBINS (BATCH * NBUCK)                   // 3128
#define SCAN_N 4096                             // padded single-block scan
#define EBLK 4096                               // edges per count/fill block
#define EPB_C (EBLK / 256)                      // 16 (count, 256 thr)
#define EPB_F (EBLK / 512)                      // 8  (fill, 512 thr)
#define NFB ((NEDGE + EBLK - 1) / EBLK)         // 391
#define CAPB 2560                               // per-bin record capacity (~mean+11sigma)
#define MAXR (CAPB / 256)                       // 10 records max per thread (sortdeg)

typedef float f4v __attribute__((ext_vector_type(4)));

// ---------- CSR build: two-level bucketing ----------

__global__ void __launch_bounds__(256) k_zero(int* __restrict__ cnt) {
    int i = blockIdx.x * 256 + threadIdx.x;
    if (i < SCAN_N) cnt[i] = 0;
}

__global__ void __launch_bounds__(256) k_count(const int* __restrict__ ei,
                                               int* __restrict__ cnt) {
    __shared__ int h[NBUCK];
    int t = threadIdx.x;
    for (int i = t; i < NBUCK; i += 256) h[i] = 0;
    __syncthreads();
    int b = blockIdx.y;
    int e0 = blockIdx.x * EBLK;
    const int* dsts = ei + ((size_t)b * 2 + 1) * NEDGE;
    for (int it = 0; it < EPB_C; ++it) {
        int e = e0 + it * 256 + t;
        if (e < NEDGE) atomicAdd(&h[dsts[e] >> 6], 1);
    }
    __syncthreads();
    for (int i = t; i < NBUCK; i += 256) {
        int c = h[i];
        if (c) atomicAdd(&cnt[b * NBUCK + i], c);
    }
}

__global__ void __launch_bounds__(256) k_scan(const int* __restrict__ cnt,
                                              int* __restrict__ off,
                                              int* __restrict__ cur) {
    __shared__ int w[256];
    int t = threadIdx.x;
    int base = t * 16;
    int loc[16];
    int s = 0;
#pragma unroll
    for (int j = 0; j < 16; j++) { loc[j] = cnt[base + j]; s += loc[j]; }
    w[t] = s;
    __syncthreads();
    for (int d = 1; d < 256; d <<= 1) {
        int v = (t >= d) ? w[t - d] : 0;
        __syncthreads();
        w[t] += v;
        __syncthreads();
    }
    int run = w[t] - s;
#pragma unroll
    for (int j = 0; j < 16; j++) {
        int i = base + j;
        off[i] = run;
        if (i < NBINS) cur[i] = run;
        run += loc[j];
    }
}

// 512 threads: 3 blocks/CU (LDS ~48KB) x 8 waves = 75% occupancy cap to hide
// rank-atomic latency. Key = (dst<<16)|src (full dst -> no sbuck array).
__global__ void __launch_bounds__(512) k_fill(const int* __restrict__ ei,
                                              const float* __restrict__ ew,
                                              int* __restrict__ cur,
                                              int2* __restrict__ rec) {
    __shared__ int h[1024];
    __shared__ int loff[1024];
    __shared__ int gbase[NBUCK];
    __shared__ int2 srec[EBLK];      // 32 KB
    __shared__ int w[512];

    int t = threadIdx.x;
    int b = blockIdx.y;
    int e0 = blockIdx.x * EBLK;
    for (int i = t; i < 1024; i += 512) h[i] = 0;
    __syncthreads();

    const size_t ebase = (size_t)b * 2 * NEDGE;
    const int* srcs = ei + ebase;
    const int* dsts = ei + ebase + NEDGE;
    const float* ws = ew + (size_t)b * NEDGE;

    int2 myrec[EPB_F];
    int mypk[EPB_F];
#pragma unroll
    for (int it = 0; it < EPB_F; ++it) {
        int e = e0 + it * 512 + t;
        int valid = e < NEDGE;
        int src = 0, dst = 0;
        float wv = 0.0f;
        if (valid) { src = srcs[e]; dst = dsts[e]; wv = ws[e]; }
        int g = dst >> 6;
        int r = 0;
        if (valid) r = atomicAdd(&h[g], 1);
        myrec[it] = make_int2((dst << 16) | src, __float_as_int(wv));
        mypk[it] = valid ? ((g << 16) | r) : -1;   // r < 4096 fits
    }
    __syncthreads();

    // scan 1024 bucket counts (2 per thread)
    int c0 = h[2 * t], c1 = h[2 * t + 1];
    int ls = c0 + c1;
    w[t] = ls;
    __syncthreads();
    for (int d = 1; d < 512; d <<= 1) {
        int v = (t >= d) ? w[t - d] : 0;
        __syncthreads();
        w[t] += v;
        __syncthreads();
    }
    int excl = w[t] - ls;
    loff[2 * t] = excl;
    loff[2 * t + 1] = excl + c0;
    __syncthreads();

    for (int i = t; i < NBUCK; i += 512) {
        int c = h[i];
        if (c) gbase[i] = atomicAdd(&cur[b * NBUCK + i], c);
    }
#pragma unroll
    for (int it = 0; it < EPB_F; ++it) {
        int pk = mypk[it];
        if (pk >= 0) {
            int g = pk >> 16, r = pk & 0xFFFF;
            srec[loff[g] + r] = myrec[it];
        }
    }
    __syncthreads();

    int nvalid = min(EBLK, NEDGE - e0);
    for (int j = t; j < nvalid; j += 512) {
        int2 rv = srec[j];
        int g = ((unsigned)rv.x) >> 22;          // dst>>6 (logical shift)
        rec[gbase[g] + (j - loff[g])] = rv;
    }
}

// ---------- numeric phase ----------

// Per bin: rank ONCE (int atomics), node-sort in LDS, write sorted records
// back to rec IN PLACE + per-node bases; compute deg in registers; write
// dinv AND the xs = dinv*x staging rows for this bucket's nodes.
__global__ void __launch_bounds__(256) k_sortdeg(const int* __restrict__ off,
                                                 int2* rec,
                                                 const float* __restrict__ x,
                                                 float* __restrict__ dinv,
                                                 float* __restrict__ xs,
                                                 int* __restrict__ nodebase) {
    __shared__ int2 srec[CAPB];      // 20.5 KB node-sorted records
    __shared__ int hh[BNODE];
    __shared__ int basev[BNODE];
    __shared__ int wsc[BNODE];

    int t = threadIdx.x;
    // same XCD mapping as k_gather2 so rec slice stays L2-warm
    int bid = blockIdx.x;
    int xcd = bid & 7;
    int b = xcd >> 1;
    int gl = ((bid >> 3) << 1) + (xcd & 1);   // 0..781, bijective
    int bin = b * NBUCK + gl;

    if (t < BNODE) hh[t] = 0;
    __syncthreads();

    int s = off[bin], e = off[bin + 1];
    const unsigned long long* rp = (const unsigned long long*)rec;

    // phase 1: load + rank by node
    int2 myrec[MAXR];
    int mypk[MAXR];
#pragma unroll
    for (int i = 0; i < MAXR; i++) {
        mypk[i] = -1;
        int j = s + i * 256 + t;
        if (j < e) {
            unsigned long long rv = rp[j];
            int key = (int)(rv & 0xFFFFFFFFull);
            myrec[i] = make_int2(key, (int)(rv >> 32));
            int node = (key >> 16) & 63;
            int r = atomicAdd(&hh[node], 1);
            mypk[i] = (r << 6) | node;
        }
    }
    __syncthreads();

    // phase 2: exclusive scan of 64 node counts
    if (t < BNODE) wsc[t] = hh[t];
    __syncthreads();
    for (int d = 1; d < BNODE; d <<= 1) {
        int v = 0;
        if (t < BNODE && t >= d) v = wsc[t - d];
        __syncthreads();
        if (t < BNODE) wsc[t] += v;
        __syncthreads();
    }
    if (t < BNODE) basev[t] = wsc[t] - hh[t];
    __syncthreads();

    // phase 3: scatter node-sorted into LDS
#pragma unroll
    for (int i = 0; i < MAXR; i++) {
        int pk = mypk[i];
        if (pk >= 0) srec[basev[pk & 63] + (pk >> 6)] = myrec[i];
    }
    __syncthreads();

    // phase 3b: sorted records back to global (in place) + per-node bases
    int cntr = e - s;
    for (int j = t; j < cntr; j += 256) rec[s + j] = srec[j];
    if (t < BNODE) nodebase[bin * BNODE + t] = s + basev[t];

    // phase 4: per-node deg in registers (4 threads/node)
    int node = t >> 2, par = t & 3;
    int rs = basev[node], cn = hh[node];
    float sum = 0.0f;
    for (int j = rs + par; j < rs + cn; j += 4)
        sum += __int_as_float(srec[j].y);
    sum += __shfl_xor(sum, 1);
    sum += __shfl_xor(sum, 2);
    float rsq = rsqrtf(1.0f + sum);           // +1 = self-loop weight

    int n = gl * BNODE + node;
    if (n >= NNODE) return;
    size_t gi = (size_t)b * NNODE + n;
    if (par == 0) dinv[gi] = rsq;
    // xs row: elements [par*4, par*4+4), pad (12..15) = 0
    f4v o = {0.f, 0.f, 0.f, 0.f};
    if (par < 3) {
        const f4v* x4 = (const f4v*)(x + gi * F_IN);
        f4v v = x4[par];
        o.x = rsq * v.x; o.y = rsq * v.y; o.z = rsq * v.z; o.w = rsq * v.w;
    }
    ((f4v*)xs)[gi * 4 + par] = o;
}

// No ranking: read node-sorted segments from global, accumulate in registers.
__global__ void __launch_bounds__(256) k_gather2(const int* __restrict__ off,
                                                 const int2* __restrict__ rec,
                                                 const int* __restrict__ nodebase,
                                                 const float* __restrict__ xs,
                                                 const float* __restrict__ dinv,
                                                 const float* __restrict__ Wm,
                                                 const float* __restrict__ bias,
                                                 float* __restrict__ out) {
    __shared__ float sW[F_IN * F_OUT];
    __shared__ float sb[F_OUT];
    __shared__ int nb[BNODE + 1];

    int t = threadIdx.x;
    int bid = blockIdx.x;
    int xcd = bid & 7;
    int b = xcd >> 1;
    int gl = ((bid >> 3) << 1) + (xcd & 1);
    int bin = b * NBUCK + gl;

    for (int i = t; i < F_IN * F_OUT; i += 256) sW[i] = Wm[i];
    if (t < F_OUT) sb[t] = bias[t];
    if (t < BNODE) nb[t] = nodebase[bin * BNODE + t];
    if (t == 0) nb[BNODE] = off[bin + 1];
    __syncthreads();

    int node = t >> 2, par = t & 3;
    int rs = nb[node], re = nb[node + 1];
    const f4v* xs4 = (const f4v*)xs + (size_t)b * NNODE * 4;
    const unsigned long long* rp = (const unsigned long long*)rec;

    float a[F_IN];
#pragma unroll
    for (int k = 0; k < F_IN; k++) a[k] = 0.0f;
    for (int j = rs + par; j < re; j += 4) {
        unsigned long long rv = rp[j];
        int key = (int)(rv & 0xFFFFFFFFull);
        float wv = __int_as_float((int)(rv >> 32));
        const f4v* xp = xs4 + (size_t)(key & 0xFFFF) * 4;
        f4v v0 = xp[0], v1 = xp[1], v2 = xp[2];
        a[0] += wv * v0.x;  a[1] += wv * v0.y;  a[2]  += wv * v0.z;  a[3]  += wv * v0.w;
        a[4] += wv * v1.x;  a[5] += wv * v1.y;  a[6]  += wv * v1.z;  a[7]  += wv * v1.w;
        a[8] += wv * v2.x;  a[9] += wv * v2.y;  a[10] += wv * v2.z;  a[11] += wv * v2.w;
    }
#pragma unroll
    for (int k = 0; k < F_IN; k++) {
        a[k] += __shfl_xor(a[k], 1);
        a[k] += __shfl_xor(a[k], 2);
    }

    int n = gl * BNODE + node;
    if (n >= NNODE) return;
    float di = dinv[(size_t)b * NNODE + n];
    const f4v* xn = xs4 + (size_t)n * 4;
    f4v s0 = xn[0], s1 = xn[1], s2 = xn[2];
    float xsn[F_IN] = {s0.x, s0.y, s0.z, s0.w, s1.x, s1.y, s1.z, s1.w,
                       s2.x, s2.y, s2.z, s2.w};
#pragma unroll
    for (int k = 0; k < F_IN; k++) a[k] = di * (a[k] + xsn[k]);

    float hv[12];
#pragma unroll
    for (int j = 0; j < 12; j++) {
        int jj = par * 12 + j;
        float v = sb[jj];
#pragma unroll
        for (int k = 0; k < F_IN; k++) v = fmaf(a[k], sW[k * F_OUT + jj], v);
        hv[j] = v;
    }
    f4v* out4 = (f4v*)out;
#pragma unroll
    for (int q = 0; q < 3; q++) {
        int sq = par * 3 + q;
        f4v v = {hv[q * 4 + 0], hv[q * 4 + 1], hv[q * 4 + 2], hv[q * 4 + 3]};
        __builtin_nontemporal_store(v, out4 + (size_t)(b * SEQ + sq) * NNODE + n);
    }
}

extern "C" void kernel_launch(void* const* d_in, const int* in_sizes, int n_in,
                              void* d_out, int out_size, void* d_ws, size_t ws_size,
                              hipStream_t stream) {
    const float* x  = (const float*)d_in[0];
    const int*   ei = (const int*)d_in[1];
    const float* ew = (const float*)d_in[2];
    const float* Wm = (const float*)d_in[3];
    const float* bv = (const float*)d_in[4];
    float* out = (float*)d_out;

    // Workspace: rec 51.2 | xs 12.8 | cnt/off/cur | dinv 0.8 | nodebase 0.8 MB
    int2*  rec = (int2*)d_ws;
    float* xs  = (float*)(rec + (size_t)BATCH * NEDGE);
    int*   cnt = (int*)(xs + (size_t)BATCH * NNODE * 16);
    int*   off = cnt + SCAN_N;
    int*   cur = off + SCAN_N;
    float* dinv = (float*)(cur + NBINS);
    int*   nodebase = (int*)(dinv + (size_t)BATCH * NNODE);

    k_zero<<<SCAN_N / 256, 256, 0, stream>>>(cnt);
    {
        dim3 grid(NFB, BATCH);
        k_count<<<grid, 256, 0, stream>>>(ei, cnt);
    }
    k_scan<<<1, 256, 0, stream>>>(cnt, off, cur);
    {
        dim3 grid(NFB, BATCH);
        k_fill<<<grid, 512, 0, stream>>>(ei, ew, cur, rec);
    }
    k_sortdeg<<<8 * (NBUCK / 2), 256, 0, stream>>>(off, rec, x, dinv, xs, nodebase);
    k_gather2<<<8 * (NBUCK / 2), 256, 0, stream>>>(off, rec, nodebase, xs, dinv, Wm, bv, out);
}